// Round 16
// baseline (75.270 us; speedup 1.0000x reference)
//
#include <hip/hip_runtime.h>
#include <hip/hip_fp16.h>
#include <math.h>

// contracting REN forward. S=8, N=64, NU=6, NY=5, NH=80, B=524288.
// Outputs: hidden (B,8) then y (B,5), concatenated flat.
// R16 = R12 k_main (f16 pairs + v_dot2_f32_f16, dual-accum scan, 1 row/thread)
//       with outputs folded into the scan loop (stall filler), plus a
//       barrier-light prep: shuffle-based Gauss-Jordan + concurrent folds.

constexpr int NH = 80;

// ---- workspace layout (uint word offsets) ----
constexpr int WS_DTT2 = 0;      // uint[64*32]  kappa*Dt[i] packed pairs (j<i else 0)
constexpr int WS_V0C  = 2048;   // uint[64*8]   per i: 4 C1 pairs, 3 D12 pairs, 1 zero
constexpr int WS_G2P  = 2560;   // uint[8*32]   (Einv@B1)[a] packed pairs
constexpr int WS_D21P = 2816;   // uint[5*32]   D21[q] packed pairs
constexpr int WS_G1P  = 2976;   // uint[8*4]    (Einv@F_)[a] packed pairs
constexpr int WS_G3P  = 3008;   // uint[8*3]    (Einv@calB_2)[a] packed pairs
constexpr int WS_C2P  = 3032;   // uint[5*4]    C2[q] packed pairs
constexpr int WS_D22P = 3052;   // uint[5*3]    D22[q] packed pairs
// float-valued words
constexpr int WS_BWF  = 3072;   // float[64]    kappa*bw/Lambda
constexpr int WS_G4   = 3136;   // float[8]     Einv@bx
constexpr int WS_BY   = 3144;   // float[5]     by

__device__ __forceinline__ unsigned pack_rn(float a, float b) {
    unsigned lo = __half_as_ushort(__float2half(a));
    unsigned hi = __half_as_ushort(__float2half(b));
    return lo | (hi << 16);
}

typedef _Float16 h2 __attribute__((ext_vector_type(2)));

__device__ __forceinline__ float dot2(unsigned c, unsigned w, float acc) {
#if __has_builtin(__builtin_amdgcn_fdot2)
    return __builtin_amdgcn_fdot2(__builtin_bit_cast(h2, c),
                                  __builtin_bit_cast(h2, w), acc, false);
#else
    float out;
    asm("v_dot2_f32_f16 %0, %1, %2, %3" : "=v"(out) : "v"(c), "v"(w), "0"(acc));
    return out;
#endif
}
__device__ __forceinline__ float lo_f(unsigned u) { return (float)__builtin_bit_cast(h2, u).x; }
__device__ __forceinline__ float hi_f(unsigned u) { return (float)__builtin_bit_cast(h2, u).y; }

// single fused prep, 512 threads:
//   stage X -> 4x4-tile gram -> {wave0: shuffle Gauss-Jordan | wave1: 1/Lambda |
//   waves2-7: Einv/Lambda-independent folds} -> remaining folds.
__global__ __launch_bounds__(512) void k_prep(
    const float* __restrict__ X,
    const float* __restrict__ calB2,
    const float* __restrict__ calD12,
    const float* __restrict__ C2,
    const float* __restrict__ D21,
    const float* __restrict__ D22,
    const float* __restrict__ Y1,
    const float* __restrict__ bias,
    float* ws)
{
    __shared__ float sX[NH * NH];
    __shared__ float sH[NH * NH];
    __shared__ float sEinv[64];
    __shared__ float sLam[64];   // 1/Lambda
    int tid = threadIdx.x;
    unsigned* wsu = (unsigned*)ws;
    const float KAPPA = 2.8853900817779268f;  // 2*log2(e)

    // stage X (1600 float4)
    for (int i = tid; i < NH * NH / 4; i += 512)
        reinterpret_cast<float4*>(sX)[i] = reinterpret_cast<const float4*>(X)[i];
    __syncthreads();

    // gram H = X^T X + eps*I, 4x4 tiles (400 tiles over a 20x20 grid)
    if (tid < 400) {
        int ta = tid / 20, tb = tid % 20;
        int a0 = 4 * ta, b0 = 4 * tb;
        float acc[4][4];
        #pragma unroll
        for (int i = 0; i < 4; i++)
            #pragma unroll
            for (int j = 0; j < 4; j++) acc[i][j] = 0.f;
        for (int k = 0; k < NH; k++) {
            float4 xa = *reinterpret_cast<const float4*>(&sX[k * NH + a0]);
            float4 xb = *reinterpret_cast<const float4*>(&sX[k * NH + b0]);
            float av[4] = { xa.x, xa.y, xa.z, xa.w };
            float bv[4] = { xb.x, xb.y, xb.z, xb.w };
            #pragma unroll
            for (int i = 0; i < 4; i++)
                #pragma unroll
                for (int j = 0; j < 4; j++) acc[i][j] += av[i] * bv[j];
        }
        #pragma unroll
        for (int i = 0; i < 4; i++) {
            #pragma unroll
            for (int j = 0; j < 4; j++) {
                float v = acc[i][j];
                if (ta == tb && i == j) v += 1e-4f;
                sH[(a0 + i) * NH + b0 + j] = v;
            }
        }
    }
    __syncthreads();

    // phase A (concurrent):
    if (tid < 64) {
        // wave 0: 8x8 Gauss-Jordan with partial pivoting, all in-register via shuffles.
        // lane = r*8+c holds element (r,c) of [M | I].
        int r = tid >> 3, c = tid & 7;
        float vm = 0.5f * (sH[r * NH + c] + sH[(72 + r) * NH + 72 + c] + Y1[r * 8 + c]);
        float vi = (r == c) ? 1.f : 0.f;
        for (int p = 0; p < 8; p++) {
            // pivot search on column p (uniform result in every lane)
            int pr = p; float best = -1.f;
            for (int r2 = p; r2 < 8; r2++) {
                float cand = fabsf(__shfl(vm, r2 * 8 + p, 64));
                if (cand > best) { best = cand; pr = r2; }
            }
            // swap rows p and pr (both halves) in one bpermute
            int srcr = (r == p) ? pr : ((r == pr) ? p : r);
            vm = __shfl(vm, srcr * 8 + c, 64);
            vi = __shfl(vi, srcr * 8 + c, 64);
            // normalize row p
            float pivv = __shfl(vm, p * 8 + p, 64);
            float inv = 1.0f / pivv;
            if (r == p) { vm *= inv; vi *= inv; }
            // eliminate other rows
            float fm = __shfl(vm, r * 8 + p, 64);
            float pm = __shfl(vm, p * 8 + c, 64);
            float pi = __shfl(vi, p * 8 + c, 64);
            if (r != p) { vm -= fm * pm; vi -= fm * pi; }
        }
        sEinv[tid] = vi;
    } else if (tid < 128) {
        int i = tid - 64;
        sLam[i] = 2.0f / sH[(8 + i) * NH + 8 + i];
    } else {
        // Einv/Lambda-independent folds
        int idx = tid - 128;            // [0, 384)
        if (idx < 160) {                 // D21P
            int q = idx / 32, p = idx % 32;
            wsu[WS_D21P + idx] = pack_rn(D21[q * 64 + 2 * p], D21[q * 64 + 2 * p + 1]);
        } else if (idx < 180) {          // C2P
            int j = idx - 160, q = j >> 2, c = j & 3;
            wsu[WS_C2P + j] = pack_rn(C2[q * 8 + 2 * c], C2[q * 8 + 2 * c + 1]);
        } else if (idx < 195) {          // D22P
            int j = idx - 180, q = j / 3, c = j % 3;
            wsu[WS_D22P + j] = pack_rn(D22[q * 6 + 2 * c], D22[q * 6 + 2 * c + 1]);
        } else if (idx < 200) {          // BY
            ws[WS_BY + idx - 195] = bias[72 + idx - 195];
        }
    }
    __syncthreads();

    // phase B: everything needing sLam / sEinv
    // DTT2: packed kappa-scaled Dt rows (j<i else 0)
    for (int idx = tid; idx < 2048; idx += 512) {
        int i = idx >> 5, p = idx & 31;
        int j0 = 2 * p, j1 = 2 * p + 1;
        float f0 = (j0 < i) ? -KAPPA * sH[(8 + i) * NH + 8 + j0] * sLam[i] : 0.f;
        float f1 = (j1 < i) ? -KAPPA * sH[(8 + i) * NH + 8 + j1] * sLam[i] : 0.f;
        wsu[WS_DTT2 + idx] = pack_rn(f0, f1);
    }
    // V0C: per-row packed C1 (4 pairs) + D12 (3 pairs) + zero
    {
        int i = tid >> 3, c = tid & 7;
        float f0 = 0.f, f1 = 0.f;
        if (c < 4) {
            f0 = -KAPPA * sH[(8 + i) * NH + 2 * c] * sLam[i];
            f1 = -KAPPA * sH[(8 + i) * NH + 2 * c + 1] * sLam[i];
        } else if (c < 7) {
            int d = 2 * (c - 4);
            f0 = KAPPA * calD12[i * 6 + d] * sLam[i];
            f1 = KAPPA * calD12[i * 6 + d + 1] * sLam[i];
        }
        wsu[WS_V0C + tid] = pack_rn(f0, f1);
    }
    if (tid < 64) ws[WS_BWF + tid] = KAPPA * bias[8 + tid] * sLam[tid];
    if (tid < 256) {                     // G2P = packed (Einv @ B1)
        int a = tid >> 5, p = tid & 31;
        float g0 = 0.f, g1 = 0.f;
        for (int k = 0; k < 8; k++) {
            g0 += sEinv[a * 8 + k] * sH[(72 + k) * NH + 8 + 2 * p];
            g1 += sEinv[a * 8 + k] * sH[(72 + k) * NH + 8 + 2 * p + 1];
        }
        wsu[WS_G2P + tid] = pack_rn(g0, g1);
    } else if (tid < 288) {              // G1P = packed (Einv @ F_)
        int j = tid - 256, a = j >> 2, c = j & 3;
        float g0 = 0.f, g1 = 0.f;
        for (int k = 0; k < 8; k++) {
            g0 += sEinv[a * 8 + k] * sH[(72 + k) * NH + 2 * c];
            g1 += sEinv[a * 8 + k] * sH[(72 + k) * NH + 2 * c + 1];
        }
        wsu[WS_G1P + j] = pack_rn(g0, g1);
    } else if (tid < 312) {              // G3P = packed (Einv @ calB_2)
        int j = tid - 288, a = j / 3, c = j % 3;
        float g0 = 0.f, g1 = 0.f;
        for (int k = 0; k < 8; k++) {
            g0 += sEinv[a * 8 + k] * calB2[k * 6 + 2 * c];
            g1 += sEinv[a * 8 + k] * calB2[k * 6 + 2 * c + 1];
        }
        wsu[WS_G3P + j] = pack_rn(g0, g1);
    } else if (tid < 320) {              // G4 = Einv @ bx
        int a = tid - 312;
        float acc = 0.f;
        for (int k = 0; k < 8; k++) acc += sEinv[a * 8 + k] * bias[k];
        ws[WS_G4 + a] = acc;
    }
}

// acc already kappa-scaled: tanh(v) = 1 - 2/(1+2^q). No clamp needed:
// exp2(+big)=inf -> rcp=0 -> +1 ; exp2(-big)=0 -> rcp(1)=1 -> -1.
__device__ __forceinline__ float tanh_scaled(float q) {
    float e = __builtin_amdgcn_exp2f(q);
    return 1.f - 2.f * __builtin_amdgcn_rcpf(1.f + e);
}

__global__ __launch_bounds__(256) void k_main(
    const float* __restrict__ xg, const float* __restrict__ ug,
    const float* __restrict__ ws, float* __restrict__ out, int B)
{
    int t = blockIdx.x * blockDim.x + threadIdx.x;
    if (t >= B) return;

    const unsigned* wsu = (const unsigned*)ws;

    // load + pack x,u
    unsigned xh[4], uh[3];
    {
        const float4* xp = reinterpret_cast<const float4*>(xg + (size_t)t * 8);
        float4 a0 = xp[0], a1 = xp[1];
        xh[0] = pack_rn(a0.x, a0.y); xh[1] = pack_rn(a0.z, a0.w);
        xh[2] = pack_rn(a1.x, a1.y); xh[3] = pack_rn(a1.z, a1.w);
        const float2* up = reinterpret_cast<const float2*>(ug + (size_t)t * 6);
        float2 c0 = up[0], c1 = up[1], c2 = up[2];
        uh[0] = pack_rn(c0.x, c0.y); uh[1] = pack_rn(c1.x, c1.y); uh[2] = pack_rn(c2.x, c2.y);
    }

    // v0 pairs (kappa-scaled), packed into sv
    unsigned sv[32];
    #pragma unroll
    for (int k = 0; k < 32; k++) {
        float a0 = ws[WS_BWF + 2 * k];
        float a1 = ws[WS_BWF + 2 * k + 1];
        #pragma unroll
        for (int c = 0; c < 4; c++) {
            a0 = dot2(wsu[WS_V0C + (2 * k) * 8 + c],     xh[c], a0);
            a1 = dot2(wsu[WS_V0C + (2 * k + 1) * 8 + c], xh[c], a1);
        }
        #pragma unroll
        for (int c = 0; c < 3; c++) {
            a0 = dot2(wsu[WS_V0C + (2 * k) * 8 + 4 + c],     uh[c], a0);
            a1 = dot2(wsu[WS_V0C + (2 * k + 1) * 8 + 4 + c], uh[c], a1);
        }
        sv[k] = pack_rn(a0, a1);
    }

    // x/u parts of outputs (packed dot2)
    float h[8];
    #pragma unroll
    for (int a = 0; a < 8; a++) {
        float acc = ws[WS_G4 + a];
        #pragma unroll
        for (int c = 0; c < 4; c++) acc = dot2(wsu[WS_G1P + a * 4 + c], xh[c], acc);
        #pragma unroll
        for (int c = 0; c < 3; c++) acc = dot2(wsu[WS_G3P + a * 3 + c], uh[c], acc);
        h[a] = acc;
    }
    float y[5];
    #pragma unroll
    for (int q = 0; q < 5; q++) {
        float acc = ws[WS_BY + q];
        #pragma unroll
        for (int c = 0; c < 4; c++) acc = dot2(wsu[WS_C2P + q * 4 + c], xh[c], acc);
        #pragma unroll
        for (int c = 0; c < 3; c++) acc = dot2(wsu[WS_D22P + q * 3 + c], uh[c], acc);
        y[q] = acc;
    }

    // triangular tanh scan with outputs folded in: after pair k's w values
    // finalize, immediately accumulate their h/y contributions (13 dot2,
    // independent of the scan's critical chain -> scheduler stall filler).
    #pragma unroll
    for (int k = 0; k < 32; k++) {
        unsigned cur = sv[k];

        float aE = lo_f(cur), aO = 0.f;
        #pragma unroll
        for (int p = 0; p < k; p += 2) aE = dot2(wsu[WS_DTT2 + (2 * k) * 32 + p], sv[p], aE);
        #pragma unroll
        for (int p = 1; p < k; p += 2) aO = dot2(wsu[WS_DTT2 + (2 * k) * 32 + p], sv[p], aO);
        float we = tanh_scaled(aE + aO);

        float bE = hi_f(cur), bO = 0.f;
        #pragma unroll
        for (int p = 0; p < k; p += 2) bE = dot2(wsu[WS_DTT2 + (2 * k + 1) * 32 + p], sv[p], bE);
        #pragma unroll
        for (int p = 1; p < k; p += 2) bO = dot2(wsu[WS_DTT2 + (2 * k + 1) * 32 + p], sv[p], bO);
        float wo = tanh_scaled(bE + bO + lo_f(wsu[WS_DTT2 + (2 * k + 1) * 32 + k]) * we);  // j=2k term

        unsigned wk = pack_rn(we, wo);
        sv[k] = wk;

        #pragma unroll
        for (int a = 0; a < 8; a++) h[a] = dot2(wsu[WS_G2P + a * 32 + k], wk, h[a]);
        #pragma unroll
        for (int q = 0; q < 5; q++) y[q] = dot2(wsu[WS_D21P + q * 32 + k], wk, y[q]);
    }

    float4* hp = reinterpret_cast<float4*>(out + (size_t)t * 8);
    hp[0] = make_float4(h[0], h[1], h[2], h[3]);
    hp[1] = make_float4(h[4], h[5], h[6], h[7]);

    float* yp = out + (size_t)B * 8 + (size_t)t * 5;
    #pragma unroll
    for (int q = 0; q < 5; q++) yp[q] = y[q];
}

extern "C" void kernel_launch(void* const* d_in, const int* in_sizes, int n_in,
                              void* d_out, int out_size, void* d_ws, size_t ws_size,
                              hipStream_t stream) {
    const float* x      = (const float*)d_in[0];
    const float* u      = (const float*)d_in[1];
    const float* X      = (const float*)d_in[2];
    const float* calB2  = (const float*)d_in[3];
    const float* C2     = (const float*)d_in[4];
    const float* calD12 = (const float*)d_in[5];
    const float* D21    = (const float*)d_in[6];
    const float* D22    = (const float*)d_in[7];
    const float* Y1     = (const float*)d_in[8];
    const float* bias   = (const float*)d_in[9];
    float* ws  = (float*)d_ws;
    float* out = (float*)d_out;
    int B = in_sizes[0] / 8;

    k_prep<<<1, 512, 0, stream>>>(X, calB2, calD12, C2, D21, D22, Y1, bias, ws);
    k_main<<<(B + 255) / 256, 256, 0, stream>>>(x, u, ws, out, B);
}

// Round 17
// 69.344 us; speedup vs baseline: 1.0855x; 1.0855x over previous
//
#include <hip/hip_runtime.h>
#include <hip/hip_fp16.h>
#include <math.h>

// contracting REN forward. S=8, N=64, NU=6, NY=5, NH=80, B=524288.
// Outputs: hidden (B,8) then y (B,5), concatenated flat.
// R17 = R12 k_main verbatim (best measured: VGPR 32, occ 60%, 56.4us)
//       + fused prep (R16 shuffle-GJ) with SYMMETRIC gram (210 tiles, mirrored).

constexpr int NH = 80;

// ---- workspace layout (uint word offsets) ----
constexpr int WS_DTT2 = 0;      // uint[64*32]  kappa*Dt[i] packed pairs (j<i else 0)
constexpr int WS_V0C  = 2048;   // uint[64*8]   per i: 4 C1 pairs, 3 D12 pairs, 1 zero
constexpr int WS_G2P  = 2560;   // uint[8*32]   (Einv@B1)[a] packed pairs
constexpr int WS_D21P = 2816;   // uint[5*32]   D21[q] packed pairs
constexpr int WS_G1P  = 2976;   // uint[8*4]    (Einv@F_)[a] packed pairs
constexpr int WS_G3P  = 3008;   // uint[8*3]    (Einv@calB_2)[a] packed pairs
constexpr int WS_C2P  = 3032;   // uint[5*4]    C2[q] packed pairs
constexpr int WS_D22P = 3052;   // uint[5*3]    D22[q] packed pairs
// float-valued words
constexpr int WS_BWF  = 3072;   // float[64]    kappa*bw/Lambda
constexpr int WS_G4   = 3136;   // float[8]     Einv@bx
constexpr int WS_BY   = 3144;   // float[5]     by

__device__ __forceinline__ unsigned pack_rn(float a, float b) {
    unsigned lo = __half_as_ushort(__float2half(a));
    unsigned hi = __half_as_ushort(__float2half(b));
    return lo | (hi << 16);
}

typedef _Float16 h2 __attribute__((ext_vector_type(2)));

__device__ __forceinline__ float dot2(unsigned c, unsigned w, float acc) {
#if __has_builtin(__builtin_amdgcn_fdot2)
    return __builtin_amdgcn_fdot2(__builtin_bit_cast(h2, c),
                                  __builtin_bit_cast(h2, w), acc, false);
#else
    float out;
    asm("v_dot2_f32_f16 %0, %1, %2, %3" : "=v"(out) : "v"(c), "v"(w), "0"(acc));
    return out;
#endif
}
__device__ __forceinline__ float lo_f(unsigned u) { return (float)__builtin_bit_cast(h2, u).x; }
__device__ __forceinline__ float hi_f(unsigned u) { return (float)__builtin_bit_cast(h2, u).y; }

// single fused prep, 512 threads:
//   stage X -> symmetric 4x4-tile gram (upper triangle, mirrored) ->
//   {wave0: shuffle Gauss-Jordan | wave1: 1/Lambda | rest: indep folds} ->
//   Einv/Lambda-dependent folds.
__global__ __launch_bounds__(512) void k_prep(
    const float* __restrict__ X,
    const float* __restrict__ calB2,
    const float* __restrict__ calD12,
    const float* __restrict__ C2,
    const float* __restrict__ D21,
    const float* __restrict__ D22,
    const float* __restrict__ Y1,
    const float* __restrict__ bias,
    float* ws)
{
    __shared__ float sX[NH * NH];
    __shared__ float sH[NH * NH];
    __shared__ float sEinv[64];
    __shared__ float sLam[64];   // 1/Lambda
    int tid = threadIdx.x;
    unsigned* wsu = (unsigned*)ws;
    const float KAPPA = 2.8853900817779268f;  // 2*log2(e)

    // stage X (1600 float4)
    for (int i = tid; i < NH * NH / 4; i += 512)
        reinterpret_cast<float4*>(sX)[i] = reinterpret_cast<const float4*>(X)[i];
    __syncthreads();

    // symmetric gram H = X^T X + eps*I: 210 upper-tri 4x4 tiles, mirror writes.
    if (tid < 210) {
        // map tid -> (ta, tb) with ta <= tb over a 20x20 tile grid
        int idx = tid, ta = 0;
        while (idx >= 20 - ta) { idx -= 20 - ta; ta++; }
        int tb = ta + idx;
        int a0 = 4 * ta, b0 = 4 * tb;
        float acc[4][4];
        #pragma unroll
        for (int i = 0; i < 4; i++)
            #pragma unroll
            for (int j = 0; j < 4; j++) acc[i][j] = 0.f;
        for (int k = 0; k < NH; k++) {
            float4 xa = *reinterpret_cast<const float4*>(&sX[k * NH + a0]);
            float4 xb = *reinterpret_cast<const float4*>(&sX[k * NH + b0]);
            float av[4] = { xa.x, xa.y, xa.z, xa.w };
            float bv[4] = { xb.x, xb.y, xb.z, xb.w };
            #pragma unroll
            for (int i = 0; i < 4; i++)
                #pragma unroll
                for (int j = 0; j < 4; j++) acc[i][j] += av[i] * bv[j];
        }
        #pragma unroll
        for (int i = 0; i < 4; i++) {
            #pragma unroll
            for (int j = 0; j < 4; j++) {
                float v = acc[i][j];
                if (ta == tb && i == j) v += 1e-4f;
                sH[(a0 + i) * NH + b0 + j] = v;
                sH[(b0 + j) * NH + a0 + i] = v;   // mirror (bit-identical sum)
            }
        }
    }
    __syncthreads();

    // phase A (concurrent):
    if (tid < 64) {
        // wave 0: 8x8 Gauss-Jordan with partial pivoting, in-register via shuffles.
        // lane = r*8+c holds element (r,c) of [M | I].
        int r = tid >> 3, c = tid & 7;
        float vm = 0.5f * (sH[r * NH + c] + sH[(72 + r) * NH + 72 + c] + Y1[r * 8 + c]);
        float vi = (r == c) ? 1.f : 0.f;
        for (int p = 0; p < 8; p++) {
            int pr = p; float best = -1.f;
            for (int r2 = p; r2 < 8; r2++) {
                float cand = fabsf(__shfl(vm, r2 * 8 + p, 64));
                if (cand > best) { best = cand; pr = r2; }
            }
            int srcr = (r == p) ? pr : ((r == pr) ? p : r);
            vm = __shfl(vm, srcr * 8 + c, 64);
            vi = __shfl(vi, srcr * 8 + c, 64);
            float pivv = __shfl(vm, p * 8 + p, 64);
            float inv = 1.0f / pivv;
            if (r == p) { vm *= inv; vi *= inv; }
            float fm = __shfl(vm, r * 8 + p, 64);
            float pm = __shfl(vm, p * 8 + c, 64);
            float pi = __shfl(vi, p * 8 + c, 64);
            if (r != p) { vm -= fm * pm; vi -= fm * pi; }
        }
        sEinv[tid] = vi;
    } else if (tid < 128) {
        int i = tid - 64;
        sLam[i] = 2.0f / sH[(8 + i) * NH + 8 + i];
    } else {
        // Einv/Lambda-independent folds
        int idx = tid - 128;            // [0, 384)
        if (idx < 160) {                 // D21P
            int q = idx / 32, p = idx % 32;
            wsu[WS_D21P + idx] = pack_rn(D21[q * 64 + 2 * p], D21[q * 64 + 2 * p + 1]);
        } else if (idx < 180) {          // C2P
            int j = idx - 160, q = j >> 2, c = j & 3;
            wsu[WS_C2P + j] = pack_rn(C2[q * 8 + 2 * c], C2[q * 8 + 2 * c + 1]);
        } else if (idx < 195) {          // D22P
            int j = idx - 180, q = j / 3, c = j % 3;
            wsu[WS_D22P + j] = pack_rn(D22[q * 6 + 2 * c], D22[q * 6 + 2 * c + 1]);
        } else if (idx < 200) {          // BY
            ws[WS_BY + idx - 195] = bias[72 + idx - 195];
        }
    }
    __syncthreads();

    // phase B: everything needing sLam / sEinv
    for (int idx = tid; idx < 2048; idx += 512) {
        int i = idx >> 5, p = idx & 31;
        int j0 = 2 * p, j1 = 2 * p + 1;
        float f0 = (j0 < i) ? -KAPPA * sH[(8 + i) * NH + 8 + j0] * sLam[i] : 0.f;
        float f1 = (j1 < i) ? -KAPPA * sH[(8 + i) * NH + 8 + j1] * sLam[i] : 0.f;
        wsu[WS_DTT2 + idx] = pack_rn(f0, f1);
    }
    {
        int i = tid >> 3, c = tid & 7;
        float f0 = 0.f, f1 = 0.f;
        if (c < 4) {
            f0 = -KAPPA * sH[(8 + i) * NH + 2 * c] * sLam[i];
            f1 = -KAPPA * sH[(8 + i) * NH + 2 * c + 1] * sLam[i];
        } else if (c < 7) {
            int d = 2 * (c - 4);
            f0 = KAPPA * calD12[i * 6 + d] * sLam[i];
            f1 = KAPPA * calD12[i * 6 + d + 1] * sLam[i];
        }
        wsu[WS_V0C + tid] = pack_rn(f0, f1);
    }
    if (tid < 64) ws[WS_BWF + tid] = KAPPA * bias[8 + tid] * sLam[tid];
    if (tid < 256) {                     // G2P = packed (Einv @ B1)
        int a = tid >> 5, p = tid & 31;
        float g0 = 0.f, g1 = 0.f;
        for (int k = 0; k < 8; k++) {
            g0 += sEinv[a * 8 + k] * sH[(72 + k) * NH + 8 + 2 * p];
            g1 += sEinv[a * 8 + k] * sH[(72 + k) * NH + 8 + 2 * p + 1];
        }
        wsu[WS_G2P + tid] = pack_rn(g0, g1);
    } else if (tid < 288) {              // G1P = packed (Einv @ F_)
        int j = tid - 256, a = j >> 2, c = j & 3;
        float g0 = 0.f, g1 = 0.f;
        for (int k = 0; k < 8; k++) {
            g0 += sEinv[a * 8 + k] * sH[(72 + k) * NH + 2 * c];
            g1 += sEinv[a * 8 + k] * sH[(72 + k) * NH + 2 * c + 1];
        }
        wsu[WS_G1P + j] = pack_rn(g0, g1);
    } else if (tid < 312) {              // G3P = packed (Einv @ calB_2)
        int j = tid - 288, a = j / 3, c = j % 3;
        float g0 = 0.f, g1 = 0.f;
        for (int k = 0; k < 8; k++) {
            g0 += sEinv[a * 8 + k] * calB2[k * 6 + 2 * c];
            g1 += sEinv[a * 8 + k] * calB2[k * 6 + 2 * c + 1];
        }
        wsu[WS_G3P + j] = pack_rn(g0, g1);
    } else if (tid < 320) {              // G4 = Einv @ bx
        int a = tid - 312;
        float acc = 0.f;
        for (int k = 0; k < 8; k++) acc += sEinv[a * 8 + k] * bias[k];
        ws[WS_G4 + a] = acc;
    }
}

// acc already kappa-scaled: tanh(v) = 1 - 2/(1+2^q). No clamp needed:
// exp2(+big)=inf -> rcp=0 -> +1 ; exp2(-big)=0 -> rcp(1)=1 -> -1.
__device__ __forceinline__ float tanh_scaled(float q) {
    float e = __builtin_amdgcn_exp2f(q);
    return 1.f - 2.f * __builtin_amdgcn_rcpf(1.f + e);
}

__global__ __launch_bounds__(256) void k_main(
    const float* __restrict__ xg, const float* __restrict__ ug,
    const float* __restrict__ ws, float* __restrict__ out, int B)
{
    int t = blockIdx.x * blockDim.x + threadIdx.x;
    if (t >= B) return;

    const unsigned* wsu = (const unsigned*)ws;

    // load + pack x,u
    unsigned xh[4], uh[3];
    {
        const float4* xp = reinterpret_cast<const float4*>(xg + (size_t)t * 8);
        float4 a0 = xp[0], a1 = xp[1];
        xh[0] = pack_rn(a0.x, a0.y); xh[1] = pack_rn(a0.z, a0.w);
        xh[2] = pack_rn(a1.x, a1.y); xh[3] = pack_rn(a1.z, a1.w);
        const float2* up = reinterpret_cast<const float2*>(ug + (size_t)t * 6);
        float2 c0 = up[0], c1 = up[1], c2 = up[2];
        uh[0] = pack_rn(c0.x, c0.y); uh[1] = pack_rn(c1.x, c1.y); uh[2] = pack_rn(c2.x, c2.y);
    }

    // v0 pairs (kappa-scaled), packed into sv
    unsigned sv[32];
    #pragma unroll
    for (int k = 0; k < 32; k++) {
        float a0 = ws[WS_BWF + 2 * k];
        float a1 = ws[WS_BWF + 2 * k + 1];
        #pragma unroll
        for (int c = 0; c < 4; c++) {
            a0 = dot2(wsu[WS_V0C + (2 * k) * 8 + c],     xh[c], a0);
            a1 = dot2(wsu[WS_V0C + (2 * k + 1) * 8 + c], xh[c], a1);
        }
        #pragma unroll
        for (int c = 0; c < 3; c++) {
            a0 = dot2(wsu[WS_V0C + (2 * k) * 8 + 4 + c],     uh[c], a0);
            a1 = dot2(wsu[WS_V0C + (2 * k + 1) * 8 + 4 + c], uh[c], a1);
        }
        sv[k] = pack_rn(a0, a1);
    }

    // x/u parts of outputs (packed dot2)
    float h[8];
    #pragma unroll
    for (int a = 0; a < 8; a++) {
        float acc = ws[WS_G4 + a];
        #pragma unroll
        for (int c = 0; c < 4; c++) acc = dot2(wsu[WS_G1P + a * 4 + c], xh[c], acc);
        #pragma unroll
        for (int c = 0; c < 3; c++) acc = dot2(wsu[WS_G3P + a * 3 + c], uh[c], acc);
        h[a] = acc;
    }
    float y[5];
    #pragma unroll
    for (int q = 0; q < 5; q++) {
        float acc = ws[WS_BY + q];
        #pragma unroll
        for (int c = 0; c < 4; c++) acc = dot2(wsu[WS_C2P + q * 4 + c], xh[c], acc);
        #pragma unroll
        for (int c = 0; c < 3; c++) acc = dot2(wsu[WS_D22P + q * 3 + c], uh[c], acc);
        y[q] = acc;
    }

    // triangular tanh scan, two rows (2k, 2k+1) per pair-slot.
    // Dual accumulators per row halve the serial dot2 chain; even/odd
    // p-chains are mutually independent (4 concurrent chains).
    #pragma unroll
    for (int k = 0; k < 32; k++) {
        unsigned cur = sv[k];

        float aE = lo_f(cur), aO = 0.f;
        #pragma unroll
        for (int p = 0; p < k; p += 2) aE = dot2(wsu[WS_DTT2 + (2 * k) * 32 + p], sv[p], aE);
        #pragma unroll
        for (int p = 1; p < k; p += 2) aO = dot2(wsu[WS_DTT2 + (2 * k) * 32 + p], sv[p], aO);
        float we = tanh_scaled(aE + aO);

        float bE = hi_f(cur), bO = 0.f;
        #pragma unroll
        for (int p = 0; p < k; p += 2) bE = dot2(wsu[WS_DTT2 + (2 * k + 1) * 32 + p], sv[p], bE);
        #pragma unroll
        for (int p = 1; p < k; p += 2) bO = dot2(wsu[WS_DTT2 + (2 * k + 1) * 32 + p], sv[p], bO);
        float wo = tanh_scaled(bE + bO + lo_f(wsu[WS_DTT2 + (2 * k + 1) * 32 + k]) * we);  // j=2k term

        sv[k] = pack_rn(we, wo);
    }

    // w contributions to outputs
    #pragma unroll
    for (int a = 0; a < 8; a++) {
        float acc = h[a];
        #pragma unroll
        for (int p = 0; p < 32; p++) acc = dot2(wsu[WS_G2P + a * 32 + p], sv[p], acc);
        h[a] = acc;
    }
    float4* hp = reinterpret_cast<float4*>(out + (size_t)t * 8);
    hp[0] = make_float4(h[0], h[1], h[2], h[3]);
    hp[1] = make_float4(h[4], h[5], h[6], h[7]);

    float* yp = out + (size_t)B * 8 + (size_t)t * 5;
    #pragma unroll
    for (int q = 0; q < 5; q++) {
        float acc = y[q];
        #pragma unroll
        for (int p = 0; p < 32; p++) acc = dot2(wsu[WS_D21P + q * 32 + p], sv[p], acc);
        yp[q] = acc;
    }
}

extern "C" void kernel_launch(void* const* d_in, const int* in_sizes, int n_in,
                              void* d_out, int out_size, void* d_ws, size_t ws_size,
                              hipStream_t stream) {
    const float* x      = (const float*)d_in[0];
    const float* u      = (const float*)d_in[1];
    const float* X      = (const float*)d_in[2];
    const float* calB2  = (const float*)d_in[3];
    const float* C2     = (const float*)d_in[4];
    const float* calD12 = (const float*)d_in[5];
    const float* D21    = (const float*)d_in[6];
    const float* D22    = (const float*)d_in[7];
    const float* Y1     = (const float*)d_in[8];
    const float* bias   = (const float*)d_in[9];
    float* ws  = (float*)d_ws;
    float* out = (float*)d_out;
    int B = in_sizes[0] / 8;

    k_prep<<<1, 512, 0, stream>>>(X, calB2, calD12, C2, D21, D22, Y1, bias, ws);
    k_main<<<(B + 255) / 256, 256, 0, stream>>>(x, u, ws, out, B);
}

// Round 18
// 68.166 us; speedup vs baseline: 1.1042x; 1.0173x over previous
//
#include <hip/hip_runtime.h>
#include <hip/hip_fp16.h>
#include <math.h>

// contracting REN forward. S=8, N=64, NU=6, NY=5, NH=80, B=524288.
// Outputs: hidden (B,8) then y (B,5), concatenated flat.
// R18 = R12/R17 k_main verbatim (VGPR 32, occ ~60%, ~56.5us)
//       + 1024-thread prep: symmetric 2x2-tile gram (820 tiles, ~all threads busy),
//         shuffle Gauss-Jordan, concurrent folds.

constexpr int NH = 80;

// ---- workspace layout (uint word offsets) ----
constexpr int WS_DTT2 = 0;      // uint[64*32]  kappa*Dt[i] packed pairs (j<i else 0)
constexpr int WS_V0C  = 2048;   // uint[64*8]   per i: 4 C1 pairs, 3 D12 pairs, 1 zero
constexpr int WS_G2P  = 2560;   // uint[8*32]   (Einv@B1)[a] packed pairs
constexpr int WS_D21P = 2816;   // uint[5*32]   D21[q] packed pairs
constexpr int WS_G1P  = 2976;   // uint[8*4]    (Einv@F_)[a] packed pairs
constexpr int WS_G3P  = 3008;   // uint[8*3]    (Einv@calB_2)[a] packed pairs
constexpr int WS_C2P  = 3032;   // uint[5*4]    C2[q] packed pairs
constexpr int WS_D22P = 3052;   // uint[5*3]    D22[q] packed pairs
// float-valued words
constexpr int WS_BWF  = 3072;   // float[64]    kappa*bw/Lambda
constexpr int WS_G4   = 3136;   // float[8]     Einv@bx
constexpr int WS_BY   = 3144;   // float[5]     by

__device__ __forceinline__ unsigned pack_rn(float a, float b) {
    unsigned lo = __half_as_ushort(__float2half(a));
    unsigned hi = __half_as_ushort(__float2half(b));
    return lo | (hi << 16);
}

typedef _Float16 h2 __attribute__((ext_vector_type(2)));

__device__ __forceinline__ float dot2(unsigned c, unsigned w, float acc) {
#if __has_builtin(__builtin_amdgcn_fdot2)
    return __builtin_amdgcn_fdot2(__builtin_bit_cast(h2, c),
                                  __builtin_bit_cast(h2, w), acc, false);
#else
    float out;
    asm("v_dot2_f32_f16 %0, %1, %2, %3" : "=v"(out) : "v"(c), "v"(w), "0"(acc));
    return out;
#endif
}
__device__ __forceinline__ float lo_f(unsigned u) { return (float)__builtin_bit_cast(h2, u).x; }
__device__ __forceinline__ float hi_f(unsigned u) { return (float)__builtin_bit_cast(h2, u).y; }

// single fused prep, 1024 threads:
//   stage X -> symmetric 2x2-tile gram (820 upper-tri tiles, mirrored) ->
//   {wave0: shuffle Gauss-Jordan | wave1: 1/Lambda | rest: indep folds} ->
//   Einv/Lambda-dependent folds.
__global__ __launch_bounds__(1024) void k_prep(
    const float* __restrict__ X,
    const float* __restrict__ calB2,
    const float* __restrict__ calD12,
    const float* __restrict__ C2,
    const float* __restrict__ D21,
    const float* __restrict__ D22,
    const float* __restrict__ Y1,
    const float* __restrict__ bias,
    float* ws)
{
    __shared__ float sX[NH * NH];
    __shared__ float sH[NH * NH];
    __shared__ float sEinv[64];
    __shared__ float sLam[64];   // 1/Lambda
    int tid = threadIdx.x;
    unsigned* wsu = (unsigned*)ws;
    const float KAPPA = 2.8853900817779268f;  // 2*log2(e)

    // stage X (1600 float4)
    for (int i = tid; i < NH * NH / 4; i += 1024)
        reinterpret_cast<float4*>(sX)[i] = reinterpret_cast<const float4*>(X)[i];
    __syncthreads();

    // symmetric gram H = X^T X + eps*I: 820 upper-tri 2x2 tiles (40x40 grid), mirrored.
    if (tid < 820) {
        // map tid -> (ta, tb) with ta <= tb over a 40x40 tile grid
        int idx = tid, ta = 0;
        while (idx >= 40 - ta) { idx -= 40 - ta; ta++; }
        int tb = ta + idx;
        int a0 = 2 * ta, b0 = 2 * tb;
        float s00 = 0.f, s01 = 0.f, s10 = 0.f, s11 = 0.f;
        for (int k = 0; k < NH; k++) {
            float2 xa = *reinterpret_cast<const float2*>(&sX[k * NH + a0]);
            float2 xb = *reinterpret_cast<const float2*>(&sX[k * NH + b0]);
            s00 += xa.x * xb.x; s01 += xa.x * xb.y;
            s10 += xa.y * xb.x; s11 += xa.y * xb.y;
        }
        if (ta == tb) { s00 += 1e-4f; s11 += 1e-4f; }
        sH[a0 * NH + b0] = s00;           sH[(a0) * NH + b0 + 1] = s01;
        sH[(a0 + 1) * NH + b0] = s10;     sH[(a0 + 1) * NH + b0 + 1] = s11;
        sH[b0 * NH + a0] = s00;           sH[(b0 + 1) * NH + a0] = s01;
        sH[b0 * NH + a0 + 1] = s10;       sH[(b0 + 1) * NH + a0 + 1] = s11;
    }
    __syncthreads();

    // phase A (concurrent):
    if (tid < 64) {
        // wave 0: 8x8 Gauss-Jordan with partial pivoting, in-register via shuffles.
        // lane = r*8+c holds element (r,c) of [M | I].
        int r = tid >> 3, c = tid & 7;
        float vm = 0.5f * (sH[r * NH + c] + sH[(72 + r) * NH + 72 + c] + Y1[r * 8 + c]);
        float vi = (r == c) ? 1.f : 0.f;
        for (int p = 0; p < 8; p++) {
            int pr = p; float best = -1.f;
            for (int r2 = p; r2 < 8; r2++) {
                float cand = fabsf(__shfl(vm, r2 * 8 + p, 64));
                if (cand > best) { best = cand; pr = r2; }
            }
            int srcr = (r == p) ? pr : ((r == pr) ? p : r);
            vm = __shfl(vm, srcr * 8 + c, 64);
            vi = __shfl(vi, srcr * 8 + c, 64);
            float pivv = __shfl(vm, p * 8 + p, 64);
            float inv = 1.0f / pivv;
            if (r == p) { vm *= inv; vi *= inv; }
            float fm = __shfl(vm, r * 8 + p, 64);
            float pm = __shfl(vm, p * 8 + c, 64);
            float pi = __shfl(vi, p * 8 + c, 64);
            if (r != p) { vm -= fm * pm; vi -= fm * pi; }
        }
        sEinv[tid] = vi;
    } else if (tid < 128) {
        int i = tid - 64;
        sLam[i] = 2.0f / sH[(8 + i) * NH + 8 + i];
    } else {
        // Einv/Lambda-independent folds
        int idx = tid - 128;
        if (idx < 160) {                 // D21P
            int q = idx / 32, p = idx % 32;
            wsu[WS_D21P + idx] = pack_rn(D21[q * 64 + 2 * p], D21[q * 64 + 2 * p + 1]);
        } else if (idx < 180) {          // C2P
            int j = idx - 160, q = j >> 2, c = j & 3;
            wsu[WS_C2P + j] = pack_rn(C2[q * 8 + 2 * c], C2[q * 8 + 2 * c + 1]);
        } else if (idx < 195) {          // D22P
            int j = idx - 180, q = j / 3, c = j % 3;
            wsu[WS_D22P + j] = pack_rn(D22[q * 6 + 2 * c], D22[q * 6 + 2 * c + 1]);
        } else if (idx < 200) {          // BY
            ws[WS_BY + idx - 195] = bias[72 + idx - 195];
        }
    }
    __syncthreads();

    // phase B: everything needing sLam / sEinv
    for (int idx = tid; idx < 2048; idx += 1024) {
        int i = idx >> 5, p = idx & 31;
        int j0 = 2 * p, j1 = 2 * p + 1;
        float f0 = (j0 < i) ? -KAPPA * sH[(8 + i) * NH + 8 + j0] * sLam[i] : 0.f;
        float f1 = (j1 < i) ? -KAPPA * sH[(8 + i) * NH + 8 + j1] * sLam[i] : 0.f;
        wsu[WS_DTT2 + idx] = pack_rn(f0, f1);
    }
    if (tid < 512) {   // V0C: per-row packed C1 (4 pairs) + D12 (3 pairs) + zero
        int i = tid >> 3, c = tid & 7;
        float f0 = 0.f, f1 = 0.f;
        if (c < 4) {
            f0 = -KAPPA * sH[(8 + i) * NH + 2 * c] * sLam[i];
            f1 = -KAPPA * sH[(8 + i) * NH + 2 * c + 1] * sLam[i];
        } else if (c < 7) {
            int d = 2 * (c - 4);
            f0 = KAPPA * calD12[i * 6 + d] * sLam[i];
            f1 = KAPPA * calD12[i * 6 + d + 1] * sLam[i];
        }
        wsu[WS_V0C + tid] = pack_rn(f0, f1);
    }
    if (tid < 64) ws[WS_BWF + tid] = KAPPA * bias[8 + tid] * sLam[tid];
    if (tid >= 512 && tid < 768) {       // G2P = packed (Einv @ B1)
        int j = tid - 512, a = j >> 5, p = j & 31;
        float g0 = 0.f, g1 = 0.f;
        for (int k = 0; k < 8; k++) {
            g0 += sEinv[a * 8 + k] * sH[(72 + k) * NH + 8 + 2 * p];
            g1 += sEinv[a * 8 + k] * sH[(72 + k) * NH + 8 + 2 * p + 1];
        }
        wsu[WS_G2P + j] = pack_rn(g0, g1);
    } else if (tid >= 768 && tid < 800) { // G1P = packed (Einv @ F_)
        int j = tid - 768, a = j >> 2, c = j & 3;
        float g0 = 0.f, g1 = 0.f;
        for (int k = 0; k < 8; k++) {
            g0 += sEinv[a * 8 + k] * sH[(72 + k) * NH + 2 * c];
            g1 += sEinv[a * 8 + k] * sH[(72 + k) * NH + 2 * c + 1];
        }
        wsu[WS_G1P + j] = pack_rn(g0, g1);
    } else if (tid >= 800 && tid < 824) { // G3P = packed (Einv @ calB_2)
        int j = tid - 800, a = j / 3, c = j % 3;
        float g0 = 0.f, g1 = 0.f;
        for (int k = 0; k < 8; k++) {
            g0 += sEinv[a * 8 + k] * calB2[k * 6 + 2 * c];
            g1 += sEinv[a * 8 + k] * calB2[k * 6 + 2 * c + 1];
        }
        wsu[WS_G3P + j] = pack_rn(g0, g1);
    } else if (tid >= 824 && tid < 832) { // G4 = Einv @ bx
        int a = tid - 824;
        float acc = 0.f;
        for (int k = 0; k < 8; k++) acc += sEinv[a * 8 + k] * bias[k];
        ws[WS_G4 + a] = acc;
    }
}

// acc already kappa-scaled: tanh(v) = 1 - 2/(1+2^q). No clamp needed:
// exp2(+big)=inf -> rcp=0 -> +1 ; exp2(-big)=0 -> rcp(1)=1 -> -1.
__device__ __forceinline__ float tanh_scaled(float q) {
    float e = __builtin_amdgcn_exp2f(q);
    return 1.f - 2.f * __builtin_amdgcn_rcpf(1.f + e);
}

__global__ __launch_bounds__(256) void k_main(
    const float* __restrict__ xg, const float* __restrict__ ug,
    const float* __restrict__ ws, float* __restrict__ out, int B)
{
    int t = blockIdx.x * blockDim.x + threadIdx.x;
    if (t >= B) return;

    const unsigned* wsu = (const unsigned*)ws;

    // load + pack x,u
    unsigned xh[4], uh[3];
    {
        const float4* xp = reinterpret_cast<const float4*>(xg + (size_t)t * 8);
        float4 a0 = xp[0], a1 = xp[1];
        xh[0] = pack_rn(a0.x, a0.y); xh[1] = pack_rn(a0.z, a0.w);
        xh[2] = pack_rn(a1.x, a1.y); xh[3] = pack_rn(a1.z, a1.w);
        const float2* up = reinterpret_cast<const float2*>(ug + (size_t)t * 6);
        float2 c0 = up[0], c1 = up[1], c2 = up[2];
        uh[0] = pack_rn(c0.x, c0.y); uh[1] = pack_rn(c1.x, c1.y); uh[2] = pack_rn(c2.x, c2.y);
    }

    // v0 pairs (kappa-scaled), packed into sv
    unsigned sv[32];
    #pragma unroll
    for (int k = 0; k < 32; k++) {
        float a0 = ws[WS_BWF + 2 * k];
        float a1 = ws[WS_BWF + 2 * k + 1];
        #pragma unroll
        for (int c = 0; c < 4; c++) {
            a0 = dot2(wsu[WS_V0C + (2 * k) * 8 + c],     xh[c], a0);
            a1 = dot2(wsu[WS_V0C + (2 * k + 1) * 8 + c], xh[c], a1);
        }
        #pragma unroll
        for (int c = 0; c < 3; c++) {
            a0 = dot2(wsu[WS_V0C + (2 * k) * 8 + 4 + c],     uh[c], a0);
            a1 = dot2(wsu[WS_V0C + (2 * k + 1) * 8 + 4 + c], uh[c], a1);
        }
        sv[k] = pack_rn(a0, a1);
    }

    // x/u parts of outputs (packed dot2)
    float h[8];
    #pragma unroll
    for (int a = 0; a < 8; a++) {
        float acc = ws[WS_G4 + a];
        #pragma unroll
        for (int c = 0; c < 4; c++) acc = dot2(wsu[WS_G1P + a * 4 + c], xh[c], acc);
        #pragma unroll
        for (int c = 0; c < 3; c++) acc = dot2(wsu[WS_G3P + a * 3 + c], uh[c], acc);
        h[a] = acc;
    }
    float y[5];
    #pragma unroll
    for (int q = 0; q < 5; q++) {
        float acc = ws[WS_BY + q];
        #pragma unroll
        for (int c = 0; c < 4; c++) acc = dot2(wsu[WS_C2P + q * 4 + c], xh[c], acc);
        #pragma unroll
        for (int c = 0; c < 3; c++) acc = dot2(wsu[WS_D22P + q * 3 + c], uh[c], acc);
        y[q] = acc;
    }

    // triangular tanh scan, two rows (2k, 2k+1) per pair-slot.
    // Dual accumulators per row halve the serial dot2 chain; even/odd
    // p-chains are mutually independent (4 concurrent chains).
    #pragma unroll
    for (int k = 0; k < 32; k++) {
        unsigned cur = sv[k];

        float aE = lo_f(cur), aO = 0.f;
        #pragma unroll
        for (int p = 0; p < k; p += 2) aE = dot2(wsu[WS_DTT2 + (2 * k) * 32 + p], sv[p], aE);
        #pragma unroll
        for (int p = 1; p < k; p += 2) aO = dot2(wsu[WS_DTT2 + (2 * k) * 32 + p], sv[p], aO);
        float we = tanh_scaled(aE + aO);

        float bE = hi_f(cur), bO = 0.f;
        #pragma unroll
        for (int p = 0; p < k; p += 2) bE = dot2(wsu[WS_DTT2 + (2 * k + 1) * 32 + p], sv[p], bE);
        #pragma unroll
        for (int p = 1; p < k; p += 2) bO = dot2(wsu[WS_DTT2 + (2 * k + 1) * 32 + p], sv[p], bO);
        float wo = tanh_scaled(bE + bO + lo_f(wsu[WS_DTT2 + (2 * k + 1) * 32 + k]) * we);  // j=2k term

        sv[k] = pack_rn(we, wo);
    }

    // w contributions to outputs
    #pragma unroll
    for (int a = 0; a < 8; a++) {
        float acc = h[a];
        #pragma unroll
        for (int p = 0; p < 32; p++) acc = dot2(wsu[WS_G2P + a * 32 + p], sv[p], acc);
        h[a] = acc;
    }
    float4* hp = reinterpret_cast<float4*>(out + (size_t)t * 8);
    hp[0] = make_float4(h[0], h[1], h[2], h[3]);
    hp[1] = make_float4(h[4], h[5], h[6], h[7]);

    float* yp = out + (size_t)B * 8 + (size_t)t * 5;
    #pragma unroll
    for (int q = 0; q < 5; q++) {
        float acc = y[q];
        #pragma unroll
        for (int p = 0; p < 32; p++) acc = dot2(wsu[WS_D21P + q * 32 + p], sv[p], acc);
        yp[q] = acc;
    }
}

extern "C" void kernel_launch(void* const* d_in, const int* in_sizes, int n_in,
                              void* d_out, int out_size, void* d_ws, size_t ws_size,
                              hipStream_t stream) {
    const float* x      = (const float*)d_in[0];
    const float* u      = (const float*)d_in[1];
    const float* X      = (const float*)d_in[2];
    const float* calB2  = (const float*)d_in[3];
    const float* C2     = (const float*)d_in[4];
    const float* calD12 = (const float*)d_in[5];
    const float* D21    = (const float*)d_in[6];
    const float* D22    = (const float*)d_in[7];
    const float* Y1     = (const float*)d_in[8];
    const float* bias   = (const float*)d_in[9];
    float* ws  = (float*)d_ws;
    float* out = (float*)d_out;
    int B = in_sizes[0] / 8;

    k_prep<<<1, 1024, 0, stream>>>(X, calB2, calD12, C2, D21, D22, Y1, bias, ws);
    k_main<<<(B + 255) / 256, 256, 0, stream>>>(x, u, ws, out, B);
}

// Round 19
// 67.722 us; speedup vs baseline: 1.1115x; 1.0065x over previous
//
#include <hip/hip_runtime.h>
#include <hip/hip_fp16.h>
#include <math.h>

// contracting REN forward. S=8, N=64, NU=6, NY=5, NH=80, B=524288.
// Outputs: hidden (B,8) then y (B,5), concatenated flat.
// R19 = R18 verbatim + wave-phase desynchronization (s_sleep stagger) in k_main.
// Hypothesis: at max occupancy all waves run identical code in lockstep, so
// their s_load/chain stalls align; staggering start phases lets one wave's
// stalls overlap another's issue bursts.

constexpr int NH = 80;

// ---- workspace layout (uint word offsets) ----
constexpr int WS_DTT2 = 0;      // uint[64*32]  kappa*Dt[i] packed pairs (j<i else 0)
constexpr int WS_V0C  = 2048;   // uint[64*8]   per i: 4 C1 pairs, 3 D12 pairs, 1 zero
constexpr int WS_G2P  = 2560;   // uint[8*32]   (Einv@B1)[a] packed pairs
constexpr int WS_D21P = 2816;   // uint[5*32]   D21[q] packed pairs
constexpr int WS_G1P  = 2976;   // uint[8*4]    (Einv@F_)[a] packed pairs
constexpr int WS_G3P  = 3008;   // uint[8*3]    (Einv@calB_2)[a] packed pairs
constexpr int WS_C2P  = 3032;   // uint[5*4]    C2[q] packed pairs
constexpr int WS_D22P = 3052;   // uint[5*3]    D22[q] packed pairs
// float-valued words
constexpr int WS_BWF  = 3072;   // float[64]    kappa*bw/Lambda
constexpr int WS_G4   = 3136;   // float[8]     Einv@bx
constexpr int WS_BY   = 3144;   // float[5]     by

__device__ __forceinline__ unsigned pack_rn(float a, float b) {
    unsigned lo = __half_as_ushort(__float2half(a));
    unsigned hi = __half_as_ushort(__float2half(b));
    return lo | (hi << 16);
}

typedef _Float16 h2 __attribute__((ext_vector_type(2)));

__device__ __forceinline__ float dot2(unsigned c, unsigned w, float acc) {
#if __has_builtin(__builtin_amdgcn_fdot2)
    return __builtin_amdgcn_fdot2(__builtin_bit_cast(h2, c),
                                  __builtin_bit_cast(h2, w), acc, false);
#else
    float out;
    asm("v_dot2_f32_f16 %0, %1, %2, %3" : "=v"(out) : "v"(c), "v"(w), "0"(acc));
    return out;
#endif
}
__device__ __forceinline__ float lo_f(unsigned u) { return (float)__builtin_bit_cast(h2, u).x; }
__device__ __forceinline__ float hi_f(unsigned u) { return (float)__builtin_bit_cast(h2, u).y; }

// single fused prep, 1024 threads (unchanged from R18).
__global__ __launch_bounds__(1024) void k_prep(
    const float* __restrict__ X,
    const float* __restrict__ calB2,
    const float* __restrict__ calD12,
    const float* __restrict__ C2,
    const float* __restrict__ D21,
    const float* __restrict__ D22,
    const float* __restrict__ Y1,
    const float* __restrict__ bias,
    float* ws)
{
    __shared__ float sX[NH * NH];
    __shared__ float sH[NH * NH];
    __shared__ float sEinv[64];
    __shared__ float sLam[64];   // 1/Lambda
    int tid = threadIdx.x;
    unsigned* wsu = (unsigned*)ws;
    const float KAPPA = 2.8853900817779268f;  // 2*log2(e)

    // stage X (1600 float4)
    for (int i = tid; i < NH * NH / 4; i += 1024)
        reinterpret_cast<float4*>(sX)[i] = reinterpret_cast<const float4*>(X)[i];
    __syncthreads();

    // symmetric gram H = X^T X + eps*I: 820 upper-tri 2x2 tiles (40x40 grid), mirrored.
    if (tid < 820) {
        int idx = tid, ta = 0;
        while (idx >= 40 - ta) { idx -= 40 - ta; ta++; }
        int tb = ta + idx;
        int a0 = 2 * ta, b0 = 2 * tb;
        float s00 = 0.f, s01 = 0.f, s10 = 0.f, s11 = 0.f;
        for (int k = 0; k < NH; k++) {
            float2 xa = *reinterpret_cast<const float2*>(&sX[k * NH + a0]);
            float2 xb = *reinterpret_cast<const float2*>(&sX[k * NH + b0]);
            s00 += xa.x * xb.x; s01 += xa.x * xb.y;
            s10 += xa.y * xb.x; s11 += xa.y * xb.y;
        }
        if (ta == tb) { s00 += 1e-4f; s11 += 1e-4f; }
        sH[a0 * NH + b0] = s00;           sH[(a0) * NH + b0 + 1] = s01;
        sH[(a0 + 1) * NH + b0] = s10;     sH[(a0 + 1) * NH + b0 + 1] = s11;
        sH[b0 * NH + a0] = s00;           sH[(b0 + 1) * NH + a0] = s01;
        sH[b0 * NH + a0 + 1] = s10;       sH[(b0 + 1) * NH + a0 + 1] = s11;
    }
    __syncthreads();

    // phase A (concurrent):
    if (tid < 64) {
        // wave 0: 8x8 Gauss-Jordan with partial pivoting, in-register via shuffles.
        int r = tid >> 3, c = tid & 7;
        float vm = 0.5f * (sH[r * NH + c] + sH[(72 + r) * NH + 72 + c] + Y1[r * 8 + c]);
        float vi = (r == c) ? 1.f : 0.f;
        for (int p = 0; p < 8; p++) {
            int pr = p; float best = -1.f;
            for (int r2 = p; r2 < 8; r2++) {
                float cand = fabsf(__shfl(vm, r2 * 8 + p, 64));
                if (cand > best) { best = cand; pr = r2; }
            }
            int srcr = (r == p) ? pr : ((r == pr) ? p : r);
            vm = __shfl(vm, srcr * 8 + c, 64);
            vi = __shfl(vi, srcr * 8 + c, 64);
            float pivv = __shfl(vm, p * 8 + p, 64);
            float inv = 1.0f / pivv;
            if (r == p) { vm *= inv; vi *= inv; }
            float fm = __shfl(vm, r * 8 + p, 64);
            float pm = __shfl(vm, p * 8 + c, 64);
            float pi = __shfl(vi, p * 8 + c, 64);
            if (r != p) { vm -= fm * pm; vi -= fm * pi; }
        }
        sEinv[tid] = vi;
    } else if (tid < 128) {
        int i = tid - 64;
        sLam[i] = 2.0f / sH[(8 + i) * NH + 8 + i];
    } else {
        int idx = tid - 128;
        if (idx < 160) {                 // D21P
            int q = idx / 32, p = idx % 32;
            wsu[WS_D21P + idx] = pack_rn(D21[q * 64 + 2 * p], D21[q * 64 + 2 * p + 1]);
        } else if (idx < 180) {          // C2P
            int j = idx - 160, q = j >> 2, c = j & 3;
            wsu[WS_C2P + j] = pack_rn(C2[q * 8 + 2 * c], C2[q * 8 + 2 * c + 1]);
        } else if (idx < 195) {          // D22P
            int j = idx - 180, q = j / 3, c = j % 3;
            wsu[WS_D22P + j] = pack_rn(D22[q * 6 + 2 * c], D22[q * 6 + 2 * c + 1]);
        } else if (idx < 200) {          // BY
            ws[WS_BY + idx - 195] = bias[72 + idx - 195];
        }
    }
    __syncthreads();

    // phase B: everything needing sLam / sEinv
    for (int idx = tid; idx < 2048; idx += 1024) {
        int i = idx >> 5, p = idx & 31;
        int j0 = 2 * p, j1 = 2 * p + 1;
        float f0 = (j0 < i) ? -KAPPA * sH[(8 + i) * NH + 8 + j0] * sLam[i] : 0.f;
        float f1 = (j1 < i) ? -KAPPA * sH[(8 + i) * NH + 8 + j1] * sLam[i] : 0.f;
        wsu[WS_DTT2 + idx] = pack_rn(f0, f1);
    }
    if (tid < 512) {   // V0C
        int i = tid >> 3, c = tid & 7;
        float f0 = 0.f, f1 = 0.f;
        if (c < 4) {
            f0 = -KAPPA * sH[(8 + i) * NH + 2 * c] * sLam[i];
            f1 = -KAPPA * sH[(8 + i) * NH + 2 * c + 1] * sLam[i];
        } else if (c < 7) {
            int d = 2 * (c - 4);
            f0 = KAPPA * calD12[i * 6 + d] * sLam[i];
            f1 = KAPPA * calD12[i * 6 + d + 1] * sLam[i];
        }
        wsu[WS_V0C + tid] = pack_rn(f0, f1);
    }
    if (tid < 64) ws[WS_BWF + tid] = KAPPA * bias[8 + tid] * sLam[tid];
    if (tid >= 512 && tid < 768) {       // G2P
        int j = tid - 512, a = j >> 5, p = j & 31;
        float g0 = 0.f, g1 = 0.f;
        for (int k = 0; k < 8; k++) {
            g0 += sEinv[a * 8 + k] * sH[(72 + k) * NH + 8 + 2 * p];
            g1 += sEinv[a * 8 + k] * sH[(72 + k) * NH + 8 + 2 * p + 1];
        }
        wsu[WS_G2P + j] = pack_rn(g0, g1);
    } else if (tid >= 768 && tid < 800) { // G1P
        int j = tid - 768, a = j >> 2, c = j & 3;
        float g0 = 0.f, g1 = 0.f;
        for (int k = 0; k < 8; k++) {
            g0 += sEinv[a * 8 + k] * sH[(72 + k) * NH + 2 * c];
            g1 += sEinv[a * 8 + k] * sH[(72 + k) * NH + 2 * c + 1];
        }
        wsu[WS_G1P + j] = pack_rn(g0, g1);
    } else if (tid >= 800 && tid < 824) { // G3P
        int j = tid - 800, a = j / 3, c = j % 3;
        float g0 = 0.f, g1 = 0.f;
        for (int k = 0; k < 8; k++) {
            g0 += sEinv[a * 8 + k] * calB2[k * 6 + 2 * c];
            g1 += sEinv[a * 8 + k] * calB2[k * 6 + 2 * c + 1];
        }
        wsu[WS_G3P + j] = pack_rn(g0, g1);
    } else if (tid >= 824 && tid < 832) { // G4
        int a = tid - 824;
        float acc = 0.f;
        for (int k = 0; k < 8; k++) acc += sEinv[a * 8 + k] * bias[k];
        ws[WS_G4 + a] = acc;
    }
}

// acc already kappa-scaled: tanh(v) = 1 - 2/(1+2^q). No clamp needed:
// exp2(+big)=inf -> rcp=0 -> +1 ; exp2(-big)=0 -> rcp(1)=1 -> -1.
__device__ __forceinline__ float tanh_scaled(float q) {
    float e = __builtin_amdgcn_exp2f(q);
    return 1.f - 2.f * __builtin_amdgcn_rcpf(1.f + e);
}

__global__ __launch_bounds__(256) void k_main(
    const float* __restrict__ xg, const float* __restrict__ ug,
    const float* __restrict__ ws, float* __restrict__ out, int B)
{
    // wave-phase desynchronization: stagger start by ~512-cycle steps over
    // 8 phases keyed by (wave-in-block, block). s_sleep doesn't consume
    // issue slots; worst-case tail cost ~3.6K cycles (~1.5us).
    {
        int ph = ((threadIdx.x >> 6) + (blockIdx.x << 2)) & 7;
        switch (ph) {
            case 1: __builtin_amdgcn_s_sleep(8);  break;
            case 2: __builtin_amdgcn_s_sleep(16); break;
            case 3: __builtin_amdgcn_s_sleep(24); break;
            case 4: __builtin_amdgcn_s_sleep(32); break;
            case 5: __builtin_amdgcn_s_sleep(40); break;
            case 6: __builtin_amdgcn_s_sleep(48); break;
            case 7: __builtin_amdgcn_s_sleep(56); break;
            default: break;
        }
    }

    int t = blockIdx.x * blockDim.x + threadIdx.x;
    if (t >= B) return;

    const unsigned* wsu = (const unsigned*)ws;

    // load + pack x,u
    unsigned xh[4], uh[3];
    {
        const float4* xp = reinterpret_cast<const float4*>(xg + (size_t)t * 8);
        float4 a0 = xp[0], a1 = xp[1];
        xh[0] = pack_rn(a0.x, a0.y); xh[1] = pack_rn(a0.z, a0.w);
        xh[2] = pack_rn(a1.x, a1.y); xh[3] = pack_rn(a1.z, a1.w);
        const float2* up = reinterpret_cast<const float2*>(ug + (size_t)t * 6);
        float2 c0 = up[0], c1 = up[1], c2 = up[2];
        uh[0] = pack_rn(c0.x, c0.y); uh[1] = pack_rn(c1.x, c1.y); uh[2] = pack_rn(c2.x, c2.y);
    }

    // v0 pairs (kappa-scaled), packed into sv
    unsigned sv[32];
    #pragma unroll
    for (int k = 0; k < 32; k++) {
        float a0 = ws[WS_BWF + 2 * k];
        float a1 = ws[WS_BWF + 2 * k + 1];
        #pragma unroll
        for (int c = 0; c < 4; c++) {
            a0 = dot2(wsu[WS_V0C + (2 * k) * 8 + c],     xh[c], a0);
            a1 = dot2(wsu[WS_V0C + (2 * k + 1) * 8 + c], xh[c], a1);
        }
        #pragma unroll
        for (int c = 0; c < 3; c++) {
            a0 = dot2(wsu[WS_V0C + (2 * k) * 8 + 4 + c],     uh[c], a0);
            a1 = dot2(wsu[WS_V0C + (2 * k + 1) * 8 + 4 + c], uh[c], a1);
        }
        sv[k] = pack_rn(a0, a1);
    }

    // x/u parts of outputs (packed dot2)
    float h[8];
    #pragma unroll
    for (int a = 0; a < 8; a++) {
        float acc = ws[WS_G4 + a];
        #pragma unroll
        for (int c = 0; c < 4; c++) acc = dot2(wsu[WS_G1P + a * 4 + c], xh[c], acc);
        #pragma unroll
        for (int c = 0; c < 3; c++) acc = dot2(wsu[WS_G3P + a * 3 + c], uh[c], acc);
        h[a] = acc;
    }
    float y[5];
    #pragma unroll
    for (int q = 0; q < 5; q++) {
        float acc = ws[WS_BY + q];
        #pragma unroll
        for (int c = 0; c < 4; c++) acc = dot2(wsu[WS_C2P + q * 4 + c], xh[c], acc);
        #pragma unroll
        for (int c = 0; c < 3; c++) acc = dot2(wsu[WS_D22P + q * 3 + c], uh[c], acc);
        y[q] = acc;
    }

    // triangular tanh scan, two rows (2k, 2k+1) per pair-slot.
    #pragma unroll
    for (int k = 0; k < 32; k++) {
        unsigned cur = sv[k];

        float aE = lo_f(cur), aO = 0.f;
        #pragma unroll
        for (int p = 0; p < k; p += 2) aE = dot2(wsu[WS_DTT2 + (2 * k) * 32 + p], sv[p], aE);
        #pragma unroll
        for (int p = 1; p < k; p += 2) aO = dot2(wsu[WS_DTT2 + (2 * k) * 32 + p], sv[p], aO);
        float we = tanh_scaled(aE + aO);

        float bE = hi_f(cur), bO = 0.f;
        #pragma unroll
        for (int p = 0; p < k; p += 2) bE = dot2(wsu[WS_DTT2 + (2 * k + 1) * 32 + p], sv[p], bE);
        #pragma unroll
        for (int p = 1; p < k; p += 2) bO = dot2(wsu[WS_DTT2 + (2 * k + 1) * 32 + p], sv[p], bO);
        float wo = tanh_scaled(bE + bO + lo_f(wsu[WS_DTT2 + (2 * k + 1) * 32 + k]) * we);  // j=2k term

        sv[k] = pack_rn(we, wo);
    }

    // w contributions to outputs
    #pragma unroll
    for (int a = 0; a < 8; a++) {
        float acc = h[a];
        #pragma unroll
        for (int p = 0; p < 32; p++) acc = dot2(wsu[WS_G2P + a * 32 + p], sv[p], acc);
        h[a] = acc;
    }
    float4* hp = reinterpret_cast<float4*>(out + (size_t)t * 8);
    hp[0] = make_float4(h[0], h[1], h[2], h[3]);
    hp[1] = make_float4(h[4], h[5], h[6], h[7]);

    float* yp = out + (size_t)B * 8 + (size_t)t * 5;
    #pragma unroll
    for (int q = 0; q < 5; q++) {
        float acc = y[q];
        #pragma unroll
        for (int p = 0; p < 32; p++) acc = dot2(wsu[WS_D21P + q * 32 + p], sv[p], acc);
        yp[q] = acc;
    }
}

extern "C" void kernel_launch(void* const* d_in, const int* in_sizes, int n_in,
                              void* d_out, int out_size, void* d_ws, size_t ws_size,
                              hipStream_t stream) {
    const float* x      = (const float*)d_in[0];
    const float* u      = (const float*)d_in[1];
    const float* X      = (const float*)d_in[2];
    const float* calB2  = (const float*)d_in[3];
    const float* C2     = (const float*)d_in[4];
    const float* calD12 = (const float*)d_in[5];
    const float* D21    = (const float*)d_in[6];
    const float* D22    = (const float*)d_in[7];
    const float* Y1     = (const float*)d_in[8];
    const float* bias   = (const float*)d_in[9];
    float* ws  = (float*)d_ws;
    float* out = (float*)d_out;
    int B = in_sizes[0] / 8;

    k_prep<<<1, 1024, 0, stream>>>(X, calB2, calD12, C2, D21, D22, Y1, bias, ws);
    k_main<<<(B + 255) / 256, 256, 0, stream>>>(x, u, ws, out, B);
}